// Round 4
// baseline (10447.324 us; speedup 1.0000x reference)
//
#include <hip/hip_runtime.h>
#include <hip/hip_bf16.h>

#define Tn 1024
#define Bn 128
#define INn 32
#define Hn 512
#define OUTn 32
#define Kn 64
#define LPAD 536

typedef __attribute__((ext_vector_type(8))) __bf16 bf16x8;
typedef __attribute__((ext_vector_type(4))) float f32x4;
typedef __attribute__((ext_vector_type(2))) unsigned int u32x2;

typedef const __attribute__((address_space(1))) void* gas_p;
typedef __attribute__((address_space(3))) void* las_p;

static __device__ __forceinline__ float bf2f(unsigned short u) {
    union { unsigned int i; float f; } c; c.i = ((unsigned int)u) << 16; return c.f;
}
static __device__ __forceinline__ unsigned short f2bf(float f) {
    union { float f; unsigned int i; } c; c.f = f;
    unsigned int x = c.i;
    return (unsigned short)((x + 0x7fffu + ((x >> 16) & 1u)) >> 16);
}
static __device__ __forceinline__ float tanh_fast(float x) {
    float xc = fminf(fmaxf(x, -10.f), 10.f);
    float e = __expf(2.f * xc);
    return (e - 1.f) * __builtin_amdgcn_rcpf(e + 1.f);
}

// ---------------- f32 -> bf16 convert (n divisible by 4) ----------------
__global__ __launch_bounds__(256) void cvt_k(const float* __restrict__ in,
                                             unsigned short* __restrict__ out, int n4) {
    int i = blockIdx.x * 256 + threadIdx.x;
    if (i < n4) {
        float4 v = ((const float4*)in)[i];
        ushort4 o;
        o.x = f2bf(v.x); o.y = f2bf(v.y); o.z = f2bf(v.z); o.w = f2bf(v.w);
        ((ushort4*)out)[i] = o;
    }
}

// ---------------- pi coefficients + combined biases ----------------
__global__ __launch_bounds__(512) void prep_small(const float* __restrict__ b_d,
                                                  const float* __restrict__ bih0, const float* __restrict__ bhh0,
                                                  const float* __restrict__ bih1, const float* __restrict__ bhh1,
                                                  float* __restrict__ pi, float* __restrict__ bias0,
                                                  float* __restrict__ bias1) {
    int i = threadIdx.x;
    float d = 0.5f / (1.0f + expf(-b_d[i]));
    float c = 1.0f;
    for (int j = 1; j <= Kn; ++j) {
        c *= ((float)(j - 1) - d) / (float)j;
        pi[(j - 1) * Hn + i] = c;
    }
    bias0[i] = bih0[i] + bhh0[i];
    bias1[i] = bih1[i] + bhh1[i];
}

// ---------------- GEMM: C[M,N](bf16) = A[M,K](bf16) . Bm[N,K](bf16)^T + bias[N](f32) --------
__global__ __launch_bounds__(256, 2) void gemm_bt(const unsigned short* __restrict__ A,
                                                  const unsigned short* __restrict__ Bm,
                                                  unsigned short* __restrict__ C,
                                                  const float* __restrict__ bias,
                                                  int M, int N, int K) {
    __shared__ unsigned short As[128 * 32];
    __shared__ unsigned short Bs[128 * 32];
    int ntile = N >> 7;
    int bm = blockIdx.x / ntile;
    int bn = blockIdx.x - bm * ntile;
    size_t m0 = (size_t)bm << 7;
    int n0 = bn << 7;
    int tid = threadIdx.x;
    int lane = tid & 63, w = tid >> 6;
    int wm = w >> 1, wn = w & 1;
    int r = lane & 15, g = lane >> 4;
    int srow = tid >> 2, sblk = tid & 3;
    f32x4 acc[4][4] = {};
    for (int k0 = 0; k0 < K; k0 += 32) {
#pragma unroll
        for (int it = 0; it < 2; ++it) {
            const unsigned short* ga = A + (m0 + it * 64 + srow) * (size_t)K + k0 + sblk * 8;
            __builtin_amdgcn_global_load_lds((gas_p)ga, (las_p)((char*)As + it * 4096 + w * 1024), 16, 0, 0);
            const unsigned short* gbp = Bm + ((size_t)(n0 + it * 64 + srow)) * (size_t)K + k0 + sblk * 8;
            __builtin_amdgcn_global_load_lds((gas_p)gbp, (las_p)((char*)Bs + it * 4096 + w * 1024), 16, 0, 0);
        }
        __syncthreads();
        bf16x8 af[4], bfr[4];
#pragma unroll
        for (int m = 0; m < 4; ++m) af[m] = *(const bf16x8*)&As[(wm * 64 + m * 16 + r) * 32 + g * 8];
#pragma unroll
        for (int n = 0; n < 4; ++n) bfr[n] = *(const bf16x8*)&Bs[(wn * 64 + n * 16 + r) * 32 + g * 8];
#pragma unroll
        for (int m = 0; m < 4; ++m)
#pragma unroll
            for (int n = 0; n < 4; ++n)
                acc[m][n] = __builtin_amdgcn_mfma_f32_16x16x32_bf16(af[m], bfr[n], acc[m][n], 0, 0, 0);
        __syncthreads();
    }
#pragma unroll
    for (int n = 0; n < 4; ++n) {
        int col = n0 + wn * 64 + n * 16 + r;
        float bv = bias[col];
#pragma unroll
        for (int m = 0; m < 4; ++m) {
            size_t row0 = m0 + wm * 64 + m * 16 + g * 4;
#pragma unroll
            for (int q = 0; q < 4; ++q)
                C[(row0 + q) * (size_t)N + col] = f2bf(acc[m][n][q] + bv);
        }
    }
}

// ---------------- causal fractional-diff filter (chunked over t) ----------------
__global__ __launch_bounds__(256, 2) void filt_k(const unsigned short* __restrict__ X,
                                                 const float* __restrict__ Pi,
                                                 unsigned short* __restrict__ Y, int t_off) {
    int tid = threadIdx.x;
    int il = tid & 63, ts = tid >> 6;
    int i = blockIdx.x * 64 + il;
    int b = blockIdx.z;
    int tbase = t_off + blockIdx.y * 128 + ts * 32;
    float xr[96];
#pragma unroll
    for (int k2 = 0; k2 < 96; ++k2) {
        int t = tbase - 64 + k2;
        xr[k2] = (t >= 0) ? bf2f(X[(size_t)t * (Bn * Hn) + b * Hn + i]) : 0.0f;
    }
    float acc[32];
#pragma unroll
    for (int tt = 0; tt < 32; ++tt) acc[tt] = xr[64 + tt];
#pragma unroll
    for (int j = 1; j <= 64; ++j) {
        float p = Pi[(j - 1) * Hn + i];
#pragma unroll
        for (int tt = 0; tt < 32; ++tt) acc[tt] += p * xr[64 + tt - j];
    }
#pragma unroll
    for (int tt = 0; tt < 32; ++tt)
        Y[(size_t)(tbase - t_off + tt) * (Bn * Hn) + b * Hn + i] = f2bf(acc[tt]);
}

// ---------------- recurrence v3: whole H per workgroup, LDS-only h exchange ----------------
// 8 wgs (one per 16-batch group), 512 thr = 8 waves at 1 wave/SIMD. Wave w owns o-rows
// [64w,64w+64): W slice 64x512 bf16 = 256 VGPRs, loaded once. h[16b][512] double-buffered
// in LDS; one barrier per step. pre[t] register-prefetched 2 steps ahead.
// Layer 0 writes hs in place over pre (store row t vs load row t+2: disjoint).
__global__ __launch_bounds__(512, 1) void rec3_k(const unsigned short* __restrict__ W,
                                                 const unsigned short* pre,
                                                 unsigned short* hs,
                                                 float* __restrict__ hfin) {
    __shared__ unsigned short hl[2][16][LPAD];
    int gb = blockIdx.x;                   // batch group 0..7
    int tid = threadIdx.x, lane = tid & 63, w = tid >> 6;
    int r = lane & 15, g = lane >> 4;
    int ob = w * 64;                       // wave's o-base
    bf16x8 wreg[4][16];                    // [row-tile m][k-tile kk], rows ob+16m+r
#pragma unroll
    for (int m = 0; m < 4; ++m)
#pragma unroll
        for (int kk = 0; kk < 16; ++kk)
            wreg[m][kk] = *(const bf16x8*)(W + (size_t)(ob + m * 16 + r) * Hn + kk * 32 + g * 8);
    int bb = gb * 16 + r;
    const unsigned short* preP = pre + (size_t)bb * Hn + ob + g * 4;   // + m*16 per tile
    unsigned short* hsP = hs ? hs + (size_t)bb * Hn + ob + g * 4 : (unsigned short*)0;
    unsigned long long pf[2][4];
#pragma unroll
    for (int m = 0; m < 4; ++m) {
        pf[0][m] = *(const unsigned long long*)(preP + m * 16);
        pf[1][m] = *(const unsigned long long*)(preP + (size_t)(Bn * Hn) + m * 16);
    }
    for (int t = 0; t < Tn; ++t) {
        int p = t & 1;
        f32x4 acc[4] = {};
        if (t > 0) {
            const unsigned short* hrow = &hl[p][r][0];
#pragma unroll
            for (int kk = 0; kk < 16; ++kk) {
                bf16x8 hb = *(const bf16x8*)(hrow + kk * 32 + g * 8);
#pragma unroll
                for (int m = 0; m < 4; ++m)
                    acc[m] = __builtin_amdgcn_mfma_f32_16x16x32_bf16(wreg[m][kk], hb, acc[m], 0, 0, 0);
            }
        }
        float hv[16];
#pragma unroll
        for (int m = 0; m < 4; ++m) {
            union { unsigned long long u; unsigned short s[4]; } pv; pv.u = pf[p][m];
#pragma unroll
            for (int q = 0; q < 4; ++q)
                hv[m * 4 + q] = tanh_fast(acc[m][q] + bf2f(pv.s[q]));
        }
        // reload pf[p] = pre[t+2] (consumed 2 steps from now; tail reload harmless/unused)
        {
            int tn = (t + 2 < Tn) ? t + 2 : t;
#pragma unroll
            for (int m = 0; m < 4; ++m)
                pf[p][m] = *(const unsigned long long*)(preP + (size_t)tn * (Bn * Hn) + m * 16);
        }
        unsigned int pk[8];
#pragma unroll
        for (int m = 0; m < 4; ++m) {
            pk[m * 2]     = (unsigned)f2bf(hv[m * 4])     | ((unsigned)f2bf(hv[m * 4 + 1]) << 16);
            pk[m * 2 + 1] = (unsigned)f2bf(hv[m * 4 + 2]) | ((unsigned)f2bf(hv[m * 4 + 3]) << 16);
        }
#pragma unroll
        for (int m = 0; m < 4; ++m) {
            u32x2 v = { pk[m * 2], pk[m * 2 + 1] };
            *(u32x2*)&hl[p ^ 1][r][ob + m * 16 + g * 4] = v;
        }
        if (hsP) {
#pragma unroll
            for (int m = 0; m < 4; ++m) {
                union { unsigned int u[2]; unsigned long long v; } o;
                o.u[0] = pk[m * 2]; o.u[1] = pk[m * 2 + 1];
                *(unsigned long long*)(hsP + (size_t)t * (Bn * Hn) + m * 16) = o.v;
            }
        }
        if (hfin && t == Tn - 1) {
            float* hf = hfin + (size_t)bb * Hn + ob + g * 4;
#pragma unroll
            for (int m = 0; m < 4; ++m) {
                hf[m * 16 + 0] = hv[m * 4 + 0];
                hf[m * 16 + 1] = hv[m * 4 + 1];
                hf[m * 16 + 2] = hv[m * 4 + 2];
                hf[m * 16 + 3] = hv[m * 4 + 3];
            }
        }
        __syncthreads();
    }
}

// ---------------- final readout ----------------
__global__ __launch_bounds__(64) void readout_k(const float* __restrict__ hfin,
                                                const float* __restrict__ Who1,
                                                const float* __restrict__ bho1,
                                                float* __restrict__ out) {
    int b = blockIdx.x;
    __shared__ float hv[Hn];
    int tid = threadIdx.x;
    for (int i = tid; i < Hn; i += 64) hv[i] = hfin[(size_t)b * Hn + i];
    __syncthreads();
    if (tid < OUTn) {
        float acc = bho1[tid];
        const float* wrow = Who1 + (size_t)tid * Hn;
#pragma unroll 8
        for (int i = 0; i < Hn; ++i) acc += wrow[i] * hv[i];
        out[b * OUTn + tid] = acc;
    }
}

extern "C" void kernel_launch(void* const* d_in, const int* in_sizes, int n_in,
                              void* d_out, int out_size, void* d_ws, size_t ws_size,
                              hipStream_t stream) {
    const float* inputs = (const float*)d_in[0];
    const float* b_d    = (const float*)d_in[1];
    const float* W_emb  = (const float*)d_in[2];
    const float* b_emb  = (const float*)d_in[3];
    const float* W_ih0  = (const float*)d_in[4];
    const float* b_ih0  = (const float*)d_in[5];
    const float* W_hh0  = (const float*)d_in[6];
    const float* b_hh0  = (const float*)d_in[7];
    const float* W_ho0  = (const float*)d_in[8];
    const float* b_ho0  = (const float*)d_in[9];
    const float* W_ih1  = (const float*)d_in[10];
    const float* b_ih1  = (const float*)d_in[11];
    const float* W_hh1  = (const float*)d_in[12];
    const float* b_hh1  = (const float*)d_in[13];
    const float* W_ho1  = (const float*)d_in[14];
    const float* b_ho1  = (const float*)d_in[15];

    char* ws = (char*)d_ws;
    size_t off = 0;
    auto alloc = [&](size_t bytes) {
        void* p = ws + off;
        off += (bytes + 255) & ~(size_t)255;
        return p;
    };
    unsigned short* B    = (unsigned short*)alloc(134217728); // resident [T,B,H] bf16
    unsigned short* Hf   = (unsigned short*)alloc(67108864);  // half-T bounce
    unsigned short* inb  = (unsigned short*)alloc(8388608);
    unsigned short* Wemb = (unsigned short*)alloc(32768);
    unsigned short* Wih0 = (unsigned short*)alloc(524288);
    unsigned short* Whh0 = (unsigned short*)alloc(524288);
    unsigned short* Who0 = (unsigned short*)alloc(524288);
    unsigned short* Wih1 = (unsigned short*)alloc(524288);
    unsigned short* Whh1 = (unsigned short*)alloc(524288);
    float* bias0 = (float*)alloc(2048);
    float* bias1 = (float*)alloc(2048);
    float* piB   = (float*)alloc(131072);
    float* hfin  = (float*)alloc(262144);
    (void)ws_size; (void)in_sizes; (void)n_in; (void)out_size;

    unsigned short* B_hi = B + (size_t)512 * Bn * Hn;
    const size_t halfBytes = 67108864;
    const int Mh = 512 * Bn;

    cvt_k<<<4096, 256, 0, stream>>>(inputs, inb, 1048576);
    cvt_k<<<16,   256, 0, stream>>>(W_emb, Wemb, 4096);
    cvt_k<<<256,  256, 0, stream>>>(W_ih0, Wih0, 65536);
    cvt_k<<<256,  256, 0, stream>>>(W_hh0, Whh0, 65536);
    cvt_k<<<256,  256, 0, stream>>>(W_ho0, Who0, 65536);
    cvt_k<<<256,  256, 0, stream>>>(W_ih1, Wih1, 65536);
    cvt_k<<<256,  256, 0, stream>>>(W_hh1, Whh1, 65536);
    prep_small<<<1, 512, 0, stream>>>(b_d, b_ih0, b_hh0, b_ih1, b_hh1, piB, bias0, bias1);

    // ---- layer 0 ----
    gemm_bt<<<4096, 256, 0, stream>>>(inb, Wemb, B, b_emb, Tn * Bn, Hn, INn);    // B = x
    filt_k<<<dim3(8, 4, 128), 256, 0, stream>>>(B, piB, Hf, 512);
    gemm_bt<<<2048, 256, 0, stream>>>(Hf, Wih0, B_hi, bias0, Mh, Hn, Hn);        // B_hi = pre0_hi
    filt_k<<<dim3(8, 4, 128), 256, 0, stream>>>(B, piB, Hf, 0);
    gemm_bt<<<2048, 256, 0, stream>>>(Hf, Wih0, B, bias0, Mh, Hn, Hn);           // B_lo = pre0_lo
    rec3_k<<<8, 512, 0, stream>>>(Whh0, B, B, nullptr);                          // B = hs0 (in place)
    gemm_bt<<<2048, 256, 0, stream>>>(B_hi, Who0, Hf, b_ho0, Mh, Hn, Hn);
    hipMemcpyAsync(B_hi, Hf, halfBytes, hipMemcpyDeviceToDevice, stream);
    gemm_bt<<<2048, 256, 0, stream>>>(B, Who0, Hf, b_ho0, Mh, Hn, Hn);
    hipMemcpyAsync(B, Hf, halfBytes, hipMemcpyDeviceToDevice, stream);           // B = y0
    // ---- layer 1 ----
    filt_k<<<dim3(8, 4, 128), 256, 0, stream>>>(B, piB, Hf, 512);
    gemm_bt<<<2048, 256, 0, stream>>>(Hf, Wih1, B_hi, bias1, Mh, Hn, Hn);        // B_hi = pre1_hi
    filt_k<<<dim3(8, 4, 128), 256, 0, stream>>>(B, piB, Hf, 0);
    gemm_bt<<<2048, 256, 0, stream>>>(Hf, Wih1, B, bias1, Mh, Hn, Hn);           // B_lo = pre1_lo
    rec3_k<<<8, 512, 0, stream>>>(Whh1, B, nullptr, hfin);
    readout_k<<<128, 64, 0, stream>>>(hfin, W_ho1, b_ho1, (float*)d_out);
}

// Round 5
// 7680.677 us; speedup vs baseline: 1.3602x; 1.3602x over previous
//
#include <hip/hip_runtime.h>
#include <hip/hip_bf16.h>

#define Tn 1024
#define Bn 128
#define INn 32
#define Hn 512
#define OUTn 32
#define Kn 64

typedef __attribute__((ext_vector_type(8))) __bf16 bf16x8;
typedef __attribute__((ext_vector_type(4))) float f32x4;
typedef __attribute__((ext_vector_type(4))) unsigned int u32x4;
typedef __attribute__((ext_vector_type(2))) unsigned int u32x2;

typedef const __attribute__((address_space(1))) void* gas_p;
typedef __attribute__((address_space(3))) void* las_p;

static __device__ __forceinline__ float bf2f(unsigned short u) {
    union { unsigned int i; float f; } c; c.i = ((unsigned int)u) << 16; return c.f;
}
static __device__ __forceinline__ unsigned short f2bf(float f) {
    union { float f; unsigned int i; } c; c.f = f;
    unsigned int x = c.i;
    return (unsigned short)((x + 0x7fffu + ((x >> 16) & 1u)) >> 16);
}
static __device__ __forceinline__ float tanh_fast(float x) {
    float xc = fminf(fmaxf(x, -10.f), 10.f);
    float e = __expf(2.f * xc);
    return (e - 1.f) * __builtin_amdgcn_rcpf(e + 1.f);
}

// ---------------- f32 -> bf16 convert (n divisible by 4) ----------------
__global__ __launch_bounds__(256) void cvt_k(const float* __restrict__ in,
                                             unsigned short* __restrict__ out, int n4) {
    int i = blockIdx.x * 256 + threadIdx.x;
    if (i < n4) {
        float4 v = ((const float4*)in)[i];
        ushort4 o;
        o.x = f2bf(v.x); o.y = f2bf(v.y); o.z = f2bf(v.z); o.w = f2bf(v.w);
        ((ushort4*)out)[i] = o;
    }
}

// ---------------- pi coefficients + combined biases ----------------
__global__ __launch_bounds__(512) void prep_small(const float* __restrict__ b_d,
                                                  const float* __restrict__ bih0, const float* __restrict__ bhh0,
                                                  const float* __restrict__ bih1, const float* __restrict__ bhh1,
                                                  float* __restrict__ pi, float* __restrict__ bias0,
                                                  float* __restrict__ bias1) {
    int i = threadIdx.x;
    float d = 0.5f / (1.0f + expf(-b_d[i]));
    float c = 1.0f;
    for (int j = 1; j <= Kn; ++j) {
        c *= ((float)(j - 1) - d) / (float)j;
        pi[(j - 1) * Hn + i] = c;
    }
    bias0[i] = bih0[i] + bhh0[i];
    bias1[i] = bih1[i] + bhh1[i];
}

// ---------------- GEMM: C[M,N](bf16) = A[M,K](bf16) . Bm[N,K](bf16)^T + bias[N](f32) --------
__global__ __launch_bounds__(256, 2) void gemm_bt(const unsigned short* __restrict__ A,
                                                  const unsigned short* __restrict__ Bm,
                                                  unsigned short* __restrict__ C,
                                                  const float* __restrict__ bias,
                                                  int M, int N, int K) {
    __shared__ unsigned short As[128 * 32];
    __shared__ unsigned short Bs[128 * 32];
    int ntile = N >> 7;
    int bm = blockIdx.x / ntile;
    int bn = blockIdx.x - bm * ntile;
    size_t m0 = (size_t)bm << 7;
    int n0 = bn << 7;
    int tid = threadIdx.x;
    int lane = tid & 63, w = tid >> 6;
    int wm = w >> 1, wn = w & 1;
    int r = lane & 15, g = lane >> 4;
    int srow = tid >> 2, sblk = tid & 3;
    f32x4 acc[4][4] = {};
    for (int k0 = 0; k0 < K; k0 += 32) {
#pragma unroll
        for (int it = 0; it < 2; ++it) {
            const unsigned short* ga = A + (m0 + it * 64 + srow) * (size_t)K + k0 + sblk * 8;
            __builtin_amdgcn_global_load_lds((gas_p)ga, (las_p)((char*)As + it * 4096 + w * 1024), 16, 0, 0);
            const unsigned short* gbp = Bm + ((size_t)(n0 + it * 64 + srow)) * (size_t)K + k0 + sblk * 8;
            __builtin_amdgcn_global_load_lds((gas_p)gbp, (las_p)((char*)Bs + it * 4096 + w * 1024), 16, 0, 0);
        }
        __syncthreads();
        bf16x8 af[4], bfr[4];
#pragma unroll
        for (int m = 0; m < 4; ++m) af[m] = *(const bf16x8*)&As[(wm * 64 + m * 16 + r) * 32 + g * 8];
#pragma unroll
        for (int n = 0; n < 4; ++n) bfr[n] = *(const bf16x8*)&Bs[(wn * 64 + n * 16 + r) * 32 + g * 8];
#pragma unroll
        for (int m = 0; m < 4; ++m)
#pragma unroll
            for (int n = 0; n < 4; ++n)
                acc[m][n] = __builtin_amdgcn_mfma_f32_16x16x32_bf16(af[m], bfr[n], acc[m][n], 0, 0, 0);
        __syncthreads();
    }
#pragma unroll
    for (int n = 0; n < 4; ++n) {
        int col = n0 + wn * 64 + n * 16 + r;
        float bv = bias[col];
#pragma unroll
        for (int m = 0; m < 4; ++m) {
            size_t row0 = m0 + wm * 64 + m * 16 + g * 4;
#pragma unroll
            for (int q = 0; q < 4; ++q)
                C[(row0 + q) * (size_t)N + col] = f2bf(acc[m][n][q] + bv);
        }
    }
}

// ---------------- causal fractional-diff filter (chunked over t) ----------------
__global__ __launch_bounds__(256, 2) void filt_k(const unsigned short* __restrict__ X,
                                                 const float* __restrict__ Pi,
                                                 unsigned short* __restrict__ Y, int t_off) {
    int tid = threadIdx.x;
    int il = tid & 63, ts = tid >> 6;
    int i = blockIdx.x * 64 + il;
    int b = blockIdx.z;
    int tbase = t_off + blockIdx.y * 128 + ts * 32;
    float xr[96];
#pragma unroll
    for (int k2 = 0; k2 < 96; ++k2) {
        int t = tbase - 64 + k2;
        xr[k2] = (t >= 0) ? bf2f(X[(size_t)t * (Bn * Hn) + b * Hn + i]) : 0.0f;
    }
    float acc[32];
#pragma unroll
    for (int tt = 0; tt < 32; ++tt) acc[tt] = xr[64 + tt];
#pragma unroll
    for (int j = 1; j <= 64; ++j) {
        float p = Pi[(j - 1) * Hn + i];
#pragma unroll
        for (int tt = 0; tt < 32; ++tt) acc[tt] += p * xr[64 + tt - j];
    }
#pragma unroll
    for (int tt = 0; tt < 32; ++tt)
        Y[(size_t)(tbase - t_off + tt) * (Bn * Hn) + b * Hn + i] = f2bf(acc[tt]);
}

// ---------------- recurrence v4: W in LDS, o-split 8, tag-in-data exchange ----------------
// 64 wgs = 8 bg (16-batch groups) x 8 og (64-o-row eighths). 256 thr = 4 waves, 1 wg/CU
// (~100KB LDS). W slice [64][512] staged to LDS once (stride 520 -> 2-way conflicts, free).
// Per step: poll all 16x512 tagged u32 of h(t) from ex (8 dwordx4/thread, done-mask),
// scatter to double-buffered h_lds; barrier; 16 MFMA/wave from LDS; tanh; publish tagged.
// ex: u32[2 par][8 bg][16 b][512 o], value = (bf16<<16)|tag, tag = fbase+t+1.
// Overwrite safety: to publish tag V a wg must consume all partners' V-1, which they
// published only after consuming our V-2 -> slot (V&1) holding V-2 is dead. ex memset
// per launch kills stale-tag aliasing across graph replays.
__global__ __launch_bounds__(256, 1) void rec4_k(const unsigned short* __restrict__ W,
                                                 const unsigned short* pre,
                                                 unsigned short* hs,
                                                 float* __restrict__ hfin,
                                                 unsigned int* ex, int fbase) {
    __shared__ unsigned short Wl[64 * 520];
    __shared__ unsigned short hl[2][16][520];
    int bid = blockIdx.x;
    int bg = bid & 7, og = bid >> 3;
    int tid = threadIdx.x, lane = tid & 63, w = tid >> 6;
    int r = lane & 15, g = lane >> 4;
    // stage W rows og*64..+64 -> Wl (row stride 520 u16; lds dest wave-uniform + lane*16)
#pragma unroll
    for (int it = 0; it < 16; ++it) {
        int row = it * 4 + w;
        const unsigned short* gsrc = W + (size_t)(og * 64 + row) * Hn + lane * 8;
        __builtin_amdgcn_global_load_lds((gas_p)gsrc, (las_p)((char*)Wl + row * 1040), 16, 0, 0);
    }
    int bb = bg * 16 + r;
    const unsigned short* preP = pre + (size_t)bb * Hn + og * 64 + w * 16 + g * 4;
    unsigned short* hsP = hs ? hs + (size_t)bb * Hn + og * 64 + w * 16 + g * 4 : (unsigned short*)0;
    int pb_b = tid >> 4, pb_o = (tid & 15) * 32;     // this thread's poll slice
    __syncthreads();                                  // W staged (vmcnt drained)
    unsigned long long pf = *(const unsigned long long*)preP;   // pre[0] fragment
    for (int t = 0; t < Tn; ++t) {
        int par = t & 1;
        if (t > 0) {
            unsigned tg = (unsigned)(fbase + t);
            const unsigned int* pb = ex + ((size_t)par * 8 + bg) * 8192 + pb_b * 512 + pb_o;
            unsigned short* hrow = &hl[par][pb_b][pb_o];
            unsigned done = 0;
            u32x4 v0, v1, v2, v3, v4, v5, v6, v7;
#define POLL1(J, VV)                                                                  \
            if (!(done & (1u << J)))                                                  \
                asm volatile("global_load_dwordx4 %0, %1, off sc1"                    \
                             : "=v"(VV) : "v"(pb + J * 4) : "memory");
#define CHK1(J, VV)                                                                   \
            if (!(done & (1u << J))) {                                                \
                if ((VV.x & 0xffffu) == tg && (VV.y & 0xffffu) == tg &&               \
                    (VV.z & 0xffffu) == tg && (VV.w & 0xffffu) == tg) {               \
                    u32x2 d = { (VV.x >> 16) | (VV.y & 0xffff0000u),                  \
                                (VV.z >> 16) | (VV.w & 0xffff0000u) };                \
                    *(u32x2*)(hrow + J * 4) = d;                                      \
                    nd |= 1u << J;                                                    \
                }                                                                     \
            }
            while (done != 0xffu) {
                POLL1(0, v0) POLL1(1, v1) POLL1(2, v2) POLL1(3, v3)
                POLL1(4, v4) POLL1(5, v5) POLL1(6, v6) POLL1(7, v7)
                asm volatile("s_waitcnt vmcnt(0)" ::: "memory");
                unsigned nd = done;
                CHK1(0, v0) CHK1(1, v1) CHK1(2, v2) CHK1(3, v3)
                CHK1(4, v4) CHK1(5, v5) CHK1(6, v6) CHK1(7, v7)
                if (nd == done) __builtin_amdgcn_s_sleep(0);
                done = nd;
            }
#undef POLL1
#undef CHK1
        }
        __syncthreads();                              // h(t) visible in hl[par]
        int tn = (t + 1 < Tn) ? t + 1 : t;
        unsigned long long qf = *(const unsigned long long*)(preP + (size_t)tn * (Bn * Hn));
        f32x4 acc = {0.f, 0.f, 0.f, 0.f};
        if (t > 0) {
            const unsigned short* wbase = Wl + (w * 16 + r) * 520;
            const unsigned short* hbase = &hl[par][r][0];
#pragma unroll
            for (int kk = 0; kk < 16; ++kk) {
                bf16x8 af = *(const bf16x8*)(wbase + kk * 32 + g * 8);
                bf16x8 bf = *(const bf16x8*)(hbase + kk * 32 + g * 8);
                acc = __builtin_amdgcn_mfma_f32_16x16x32_bf16(af, bf, acc, 0, 0, 0);
            }
        }
        union { unsigned long long u; unsigned short s[4]; } pv; pv.u = pf;
        pf = qf;
        float h0 = tanh_fast(acc[0] + bf2f(pv.s[0]));
        float h1 = tanh_fast(acc[1] + bf2f(pv.s[1]));
        float h2 = tanh_fast(acc[2] + bf2f(pv.s[2]));
        float h3 = tanh_fast(acc[3] + bf2f(pv.s[3]));
        unsigned int b0 = f2bf(h0), b1 = f2bf(h1), b2 = f2bf(h2), b3 = f2bf(h3);
        unsigned tv = (unsigned)(fbase + t + 1);
        u32x4 sv = { (b0 << 16) | tv, (b1 << 16) | tv, (b2 << 16) | tv, (b3 << 16) | tv };
        unsigned int* wp = ex + ((size_t)((t + 1) & 1) * 8 + bg) * 8192 + r * 512 + og * 64 + w * 16 + g * 4;
        asm volatile("global_store_dwordx4 %0, %1, off sc1" :: "v"(wp), "v"(sv) : "memory");
        if (hsP) {
            union { unsigned int u[2]; unsigned long long v; } o;
            o.u[0] = b0 | (b1 << 16); o.u[1] = b2 | (b3 << 16);
            *(unsigned long long*)(hsP + (size_t)t * (Bn * Hn)) = o.v;
        }
        if (hfin && t == Tn - 1) {
            float* hf = hfin + (size_t)bb * Hn + og * 64 + w * 16 + g * 4;
            hf[0] = h0; hf[1] = h1; hf[2] = h2; hf[3] = h3;
        }
    }
}

// ---------------- final readout ----------------
__global__ __launch_bounds__(64) void readout_k(const float* __restrict__ hfin,
                                                const float* __restrict__ Who1,
                                                const float* __restrict__ bho1,
                                                float* __restrict__ out) {
    int b = blockIdx.x;
    __shared__ float hv[Hn];
    int tid = threadIdx.x;
    for (int i = tid; i < Hn; i += 64) hv[i] = hfin[(size_t)b * Hn + i];
    __syncthreads();
    if (tid < OUTn) {
        float acc = bho1[tid];
        const float* wrow = Who1 + (size_t)tid * Hn;
#pragma unroll 8
        for (int i = 0; i < Hn; ++i) acc += wrow[i] * hv[i];
        out[b * OUTn + tid] = acc;
    }
}

extern "C" void kernel_launch(void* const* d_in, const int* in_sizes, int n_in,
                              void* d_out, int out_size, void* d_ws, size_t ws_size,
                              hipStream_t stream) {
    const float* inputs = (const float*)d_in[0];
    const float* b_d    = (const float*)d_in[1];
    const float* W_emb  = (const float*)d_in[2];
    const float* b_emb  = (const float*)d_in[3];
    const float* W_ih0  = (const float*)d_in[4];
    const float* b_ih0  = (const float*)d_in[5];
    const float* W_hh0  = (const float*)d_in[6];
    const float* b_hh0  = (const float*)d_in[7];
    const float* W_ho0  = (const float*)d_in[8];
    const float* b_ho0  = (const float*)d_in[9];
    const float* W_ih1  = (const float*)d_in[10];
    const float* b_ih1  = (const float*)d_in[11];
    const float* W_hh1  = (const float*)d_in[12];
    const float* b_hh1  = (const float*)d_in[13];
    const float* W_ho1  = (const float*)d_in[14];
    const float* b_ho1  = (const float*)d_in[15];

    char* ws = (char*)d_ws;
    size_t off = 0;
    auto alloc = [&](size_t bytes) {
        void* p = ws + off;
        off += (bytes + 255) & ~(size_t)255;
        return p;
    };
    unsigned short* B    = (unsigned short*)alloc(134217728); // resident [T,B,H] bf16
    unsigned short* Hf   = (unsigned short*)alloc(67108864);  // half-T bounce
    unsigned short* inb  = (unsigned short*)alloc(8388608);
    unsigned short* Wemb = (unsigned short*)alloc(32768);
    unsigned short* Wih0 = (unsigned short*)alloc(524288);
    unsigned short* Whh0 = (unsigned short*)alloc(524288);
    unsigned short* Who0 = (unsigned short*)alloc(524288);
    unsigned short* Wih1 = (unsigned short*)alloc(524288);
    unsigned short* Whh1 = (unsigned short*)alloc(524288);
    float* bias0 = (float*)alloc(2048);
    float* bias1 = (float*)alloc(2048);
    float* piB   = (float*)alloc(131072);
    unsigned int* ex = (unsigned int*)alloc(524288);          // [2][8][16][512] u32
    float* hfin  = (float*)alloc(262144);
    (void)ws_size; (void)in_sizes; (void)n_in; (void)out_size;

    unsigned short* B_hi = B + (size_t)512 * Bn * Hn;
    const size_t halfBytes = 67108864;
    const int Mh = 512 * Bn;

    hipMemsetAsync(ex, 0, 524288, stream);
    cvt_k<<<4096, 256, 0, stream>>>(inputs, inb, 1048576);
    cvt_k<<<16,   256, 0, stream>>>(W_emb, Wemb, 4096);
    cvt_k<<<256,  256, 0, stream>>>(W_ih0, Wih0, 65536);
    cvt_k<<<256,  256, 0, stream>>>(W_hh0, Whh0, 65536);
    cvt_k<<<256,  256, 0, stream>>>(W_ho0, Who0, 65536);
    cvt_k<<<256,  256, 0, stream>>>(W_ih1, Wih1, 65536);
    cvt_k<<<256,  256, 0, stream>>>(W_hh1, Whh1, 65536);
    prep_small<<<1, 512, 0, stream>>>(b_d, b_ih0, b_hh0, b_ih1, b_hh1, piB, bias0, bias1);

    // ---- layer 0 ----
    gemm_bt<<<4096, 256, 0, stream>>>(inb, Wemb, B, b_emb, Tn * Bn, Hn, INn);    // B = x
    filt_k<<<dim3(8, 4, 128), 256, 0, stream>>>(B, piB, Hf, 512);
    gemm_bt<<<2048, 256, 0, stream>>>(Hf, Wih0, B_hi, bias0, Mh, Hn, Hn);        // B_hi = pre0_hi
    filt_k<<<dim3(8, 4, 128), 256, 0, stream>>>(B, piB, Hf, 0);
    gemm_bt<<<2048, 256, 0, stream>>>(Hf, Wih0, B, bias0, Mh, Hn, Hn);           // B_lo = pre0_lo
    rec4_k<<<64, 256, 0, stream>>>(Whh0, B, B, nullptr, ex, 0);                  // B = hs0 (in place)
    gemm_bt<<<2048, 256, 0, stream>>>(B_hi, Who0, Hf, b_ho0, Mh, Hn, Hn);
    hipMemcpyAsync(B_hi, Hf, halfBytes, hipMemcpyDeviceToDevice, stream);
    gemm_bt<<<2048, 256, 0, stream>>>(B, Who0, Hf, b_ho0, Mh, Hn, Hn);
    hipMemcpyAsync(B, Hf, halfBytes, hipMemcpyDeviceToDevice, stream);           // B = y0
    // ---- layer 1 ----
    filt_k<<<dim3(8, 4, 128), 256, 0, stream>>>(B, piB, Hf, 512);
    gemm_bt<<<2048, 256, 0, stream>>>(Hf, Wih1, B_hi, bias1, Mh, Hn, Hn);        // B_hi = pre1_hi
    filt_k<<<dim3(8, 4, 128), 256, 0, stream>>>(B, piB, Hf, 0);
    gemm_bt<<<2048, 256, 0, stream>>>(Hf, Wih1, B, bias1, Mh, Hn, Hn);           // B_lo = pre1_lo
    rec4_k<<<64, 256, 0, stream>>>(Whh1, B, nullptr, hfin, ex, 1024);
    readout_k<<<128, 64, 0, stream>>>(hfin, W_ho1, b_ho1, (float*)d_out);
}